// Round 4
// baseline (116193.530 us; speedup 1.0000x reference)
//
#include <hip/hip_runtime.h>
#include <math.h>

#define SD   2048
#define HD   1024
#define TPB  1024   // 16 waves
#define NBLK 128

// ---- ws layout (float offsets); first 4KB = barrier flags ----
#define E_OFF     1024
#define H0_OFF    3072
#define INP_OFF   4096
#define X_OFF     5120
#define CTXP_OFF  6144                     // MODE0 only: 16*HD
#define M_OFF     24576                    // M[1024][2048]
#define M_SZ      (HD * SD)
#define XH_OFF    (M_OFF + M_SZ)           // xh[(SD+1)][HD]
#define XH_SZ     ((SD + 1) * HD)
#define WS_NEED_M  ((size_t)(M_OFF + M_SZ) * 4)
#define WS_NEED_XH ((size_t)(XH_OFF + XH_SZ) * 4)

// ---- smem layout (float offsets) ----
#define SM_X   0
#define SM_H0  1024
#define SM_E   2048      // also SM_HID in epilogue
#define SM_V   4096
#define SM_G   5120
#define SM_C0  5152
#define SM_C1  5160
#define SM_CLS 5168
#define SM_SCR 6144      // MODE0 scratch (2048)
#define SM_FLOATS 9216   // 36 KB (prologue uses 0..8191 for enc staging)

typedef unsigned long long u64;

__device__ __forceinline__ float ldcf(const float* p) {
  return __hip_atomic_load(p, __ATOMIC_RELAXED, __HIP_MEMORY_SCOPE_AGENT);
}
__device__ __forceinline__ float2 ldc2(const float* p) {
  u64 u = __hip_atomic_load((const u64*)p, __ATOMIC_RELAXED, __HIP_MEMORY_SCOPE_AGENT);
  union { u64 u; float2 f; } c; c.u = u; return c.f;
}
__device__ __forceinline__ void stcf(float* p, float v) {
  __hip_atomic_store(p, v, __ATOMIC_RELAXED, __HIP_MEMORY_SCOPE_AGENT);
}
__device__ __forceinline__ unsigned ldb(const unsigned* p) {
  return __hip_atomic_load(p, __ATOMIC_RELAXED, __HIP_MEMORY_SCOPE_AGENT);
}
__device__ __forceinline__ void stb(unsigned* p, unsigned v) {
  __hip_atomic_store(p, v, __ATOMIC_RELAXED, __HIP_MEMORY_SCOPE_AGENT);
}

__device__ __forceinline__ float dot4(float4 a, float4 b) {
  return a.x * b.x + a.y * b.y + a.z * b.z + a.w * b.w;
}
__device__ __forceinline__ float wred(float v) {
  v += __shfl_xor(v, 32, 64); v += __shfl_xor(v, 16, 64);
  v += __shfl_xor(v, 8, 64);  v += __shfl_xor(v, 4, 64);
  v += __shfl_xor(v, 2, 64);  v += __shfl_xor(v, 1, 64);
  return v;
}
__device__ __forceinline__ float sigm(float x) { return 1.0f / (1.0f + __expf(-x)); }

// arrive: drain this block's data stores (syncthreads -> vmcnt(0)), set flag
__device__ __forceinline__ void bar_arrive(unsigned* bar, unsigned ep) {
  __syncthreads();
  if (threadIdx.x == 0) stb(bar + blockIdx.x, ep);
}
// wait: wave0 polls ALL flags (1 LLC RT to detect), then stages next phase's
// state ws->LDS itself, then one syncthreads releases the block.
__device__ __forceinline__ void bar_wait_stage(unsigned* bar, unsigned ep,
                                               float* d0, const float* s0, int n0,
                                               float* d1, const float* s1, int n1) {
  if (threadIdx.x < 64) {
    const int lane = threadIdx.x;
    unsigned m;
    do {
      unsigned a = ldb(bar + lane), b = ldb(bar + 64 + lane);
      m = a < b ? a : b;
#pragma unroll
      for (int s = 32; s; s >>= 1) {
        unsigned o = (unsigned)__shfl_xor((int)m, s, 64);
        m = m < o ? m : o;
      }
    } while (m < ep);
    if (d0) for (int i = lane; i < n0; i += 64) *(float2*)(d0 + 2 * i) = ldc2(s0 + 2 * i);
    if (d1) for (int i = lane; i < n1; i += 64) *(float2*)(d1 + 2 * i) = ldc2(s1 + 2 * i);
  }
  __syncthreads();
}

// MODE<2 in-loop classifier (block NBLK-1, inside barrier window)
__device__ void classifier_block(const float* smx, const float* __restrict__ lin1_w,
                                 const float* __restrict__ lin1_b,
                                 const float* __restrict__ lin2_w,
                                 const float* __restrict__ lin2_b,
                                 float* __restrict__ out2, float* cls) {
  const int tid = threadIdx.x, wid = tid >> 6, lane = tid & 63;
#pragma unroll
  for (int oi = 0; oi < 4; ++oi) {
    const int o = wid * 4 + oi;
    float acc = 0.f;
#pragma unroll
    for (int it = 0; it < 4; ++it)
      acc += dot4(*(const float4*)(lin1_w + (size_t)o * HD + it * 256 + lane * 4),
                  *(const float4*)(smx + it * 256 + lane * 4));
    acc = wred(acc);
    if (lane == 0) cls[o] = fmaxf(acc + lin1_b[o], 0.f);
  }
  __syncthreads();
  if (tid == 0) {
    float l0 = lin2_b[0], l1 = lin2_b[1];
#pragma unroll
    for (int j = 0; j < 64; ++j) {
      l0 += lin2_w[j] * cls[j];
      l1 += lin2_w[64 + j] * cls[j];
    }
    float m = fmaxf(l0, l1);
    float e0 = __expf(l0 - m), e1 = __expf(l1 - m);
    float inv = 1.f / (e0 + e1);
    out2[0] = e0 * inv; out2[1] = e1 * inv;
  }
  __syncthreads();
}

template <int MODE>   // 2: M+xhist, 1: M only, 0: neither
__global__ void __launch_bounds__(TPB, 4)
decoder_kernel(const float* __restrict__ enc, const float* __restrict__ attn_w,
               const float* __restrict__ attn_b, const float* __restrict__ comb_w,
               const float* __restrict__ comb_b, const float* __restrict__ w_ih,
               const float* __restrict__ w_hh, const float* __restrict__ b_ih,
               const float* __restrict__ b_hh, const float* __restrict__ lin1_w,
               const float* __restrict__ lin1_b, const float* __restrict__ lin2_w,
               const float* __restrict__ lin2_b, const float* __restrict__ hidden,
               const float* __restrict__ cell, float* __restrict__ out,
               float* __restrict__ ws) {
  __shared__ __align__(16) float smem[SM_FLOATS];
  const int tid = threadIdx.x, wid = tid >> 6, lane = tid & 63;
  const int bid = blockIdx.x;
  unsigned* bar = (unsigned*)ws;
  unsigned ep = 0;

  // ================= prologue =================
  if (MODE >= 1) {
    // M[j,i] = comb_w[j,1024:] . enc[i,:]; 16 j-tiles(64) x 8 i-tiles(256)
    const int j0 = (bid >> 3) * 64, i0 = (bid & 7) * 256;
    for (int ib = 0; ib < 32; ++ib) {
      const int rl = tid >> 7, c8 = (tid & 127) * 8;
      const float* src = enc + (size_t)(i0 + ib * 8 + rl) * HD + c8;
      *(float4*)(smem + rl * HD + c8)     = *(const float4*)src;
      *(float4*)(smem + rl * HD + c8 + 4) = *(const float4*)(src + 4);
      __syncthreads();
#pragma unroll 1
      for (int r = 0; r < 4; ++r) {
        const int j = j0 + wid * 4 + r;
        const float* cw = comb_w + (size_t)j * 2048 + 1024;
        for (int ii = 0; ii < 8; ++ii) {
          float acc = 0.f;
#pragma unroll
          for (int it = 0; it < 4; ++it)
            acc += dot4(*(const float4*)(cw + it * 256 + lane * 4),
                        *(const float4*)(smem + ii * HD + it * 256 + lane * 4));
          acc = wred(acc);
          if (lane == 0) stcf(ws + M_OFF + (size_t)j * SD + (i0 + ib * 8 + ii), acc);
        }
      }
      __syncthreads();
    }
  }
  // recurrent-state init
  if (bid == 0) {
    stcf(ws + H0_OFF + tid, hidden[tid]);
    float* xr0 = (MODE == 2) ? (ws + XH_OFF) : (ws + X_OFF);
    stcf(xr0 + tid, 0.f);
  }
  if (tid < 8) {
    smem[SM_C0 + tid] = cell[bid * 8 + tid];
    smem[SM_C1 + tid] = cell[HD + bid * 8 + tid];
  }
  bar_arrive(bar, ++ep);

  // ================= main loop =================
  for (int t = 0; t < SD; ++t) {
    const float* xrow_ld = (MODE == 2) ? (ws + XH_OFF + (size_t)t * HD) : (ws + X_OFF);
    float* xrow_st = (MODE == 2) ? (ws + XH_OFF + (size_t)(t + 1) * HD) : (ws + X_OFF);

    // ---- A: e[r] = exp(attn_w[r]@[x;h0] + b), 1 row/wave ----
    bar_wait_stage(bar, ep, smem + SM_X, xrow_ld, 512, smem + SM_H0, ws + H0_OFF, 512);
    {
      const int r = bid * 16 + wid;
      const float* wr = attn_w + (size_t)r * 2048;
      float acc = 0.f;
#pragma unroll
      for (int it = 0; it < 4; ++it) {
        acc += dot4(*(const float4*)(wr + it * 256 + lane * 4),
                    *(const float4*)(smem + SM_X + it * 256 + lane * 4));
        acc += dot4(*(const float4*)(wr + 1024 + it * 256 + lane * 4),
                    *(const float4*)(smem + SM_H0 + it * 256 + lane * 4));
      }
      acc = wred(acc);
      if (lane == 0) stcf(ws + E_OFF + r, __expf(acc + attn_b[r]));
    }
    bar_arrive(bar, ++ep);
    if (MODE < 2 && bid == NBLK - 1 && t > 0)
      classifier_block(smem + SM_X, lin1_w, lin1_b, lin2_w, lin2_b,
                       out + (size_t)(t - 1) * 2, smem + SM_CLS);

    // ---- B: inp = relu(Wx@x + (M@e)/sum + b) ----
    bar_wait_stage(bar, ep, smem + SM_E, ws + E_OFF, 1024, nullptr, nullptr, 0);
    if (MODE >= 1) {
      if (wid < 8) {
        const int j = bid * 8 + wid;
        float4 e4[8];
#pragma unroll
        for (int it = 0; it < 8; ++it)
          e4[it] = *(const float4*)(smem + SM_E + it * 256 + lane * 4);
        float s = 0.f;
#pragma unroll
        for (int it = 0; it < 8; ++it) s += e4[it].x + e4[it].y + e4[it].z + e4[it].w;
        const float invs = 1.f / wred(s);
        float ax = 0.f;
#pragma unroll
        for (int it = 0; it < 4; ++it)
          ax += dot4(*(const float4*)(comb_w + (size_t)j * 2048 + it * 256 + lane * 4),
                     *(const float4*)(smem + SM_X + it * 256 + lane * 4));
        float am = 0.f;
#pragma unroll
        for (int it = 0; it < 8; ++it)
          am += dot4(*(const float4*)(ws + M_OFF + (size_t)j * SD + it * 256 + lane * 4), e4[it]);
        float acc = wred(ax + invs * am);
        if (lane == 0) stcf(ws + INP_OFF + j, fmaxf(acc + comb_b[j], 0.f));
      }
      bar_arrive(bar, ++ep);
    } else {
      // B1: ctx partials (16 i-chunks x 8 col-slices)
      {
        const int chunk = bid >> 3, cb = (bid & 7) * 128;
        float a0 = 0.f, a1 = 0.f;
        for (int ii = 0; ii < 8; ++ii) {
          const int i = chunk * 128 + wid * 8 + ii;
          float e = smem[SM_E + i];
          const float* er = enc + (size_t)i * HD + cb + lane * 2;
          a0 += e * er[0]; a1 += e * er[1];
        }
        smem[SM_SCR + wid * 128 + lane * 2] = a0;
        smem[SM_SCR + wid * 128 + lane * 2 + 1] = a1;
        __syncthreads();
        if (tid < 128) {
          float s = 0.f;
#pragma unroll
          for (int w = 0; w < 16; ++w) s += smem[SM_SCR + w * 128 + tid];
          stcf(ws + CTXP_OFF + chunk * HD + cb + tid, s);
        }
      }
      bar_arrive(bar, ++ep);
      bar_wait_stage(bar, ep, nullptr, nullptr, 0, nullptr, nullptr, 0);
      // B2: reduce ctx, inp rows
      if (wid == 0) {
        float s = 0.f;
#pragma unroll
        for (int it = 0; it < 8; ++it) {
          float4 e4 = *(const float4*)(smem + SM_E + it * 256 + lane * 4);
          s += e4.x + e4.y + e4.z + e4.w;
        }
        s = wred(s);
        if (lane == 0) smem[SM_G] = 1.f / s;
      }
      __syncthreads();
      {
        const float invs = smem[SM_G];
        if (tid < 512) {
          float sx = 0.f, sy = 0.f;
#pragma unroll
          for (int ch = 0; ch < 16; ++ch) {
            float2 p2 = ldc2(ws + CTXP_OFF + ch * HD + tid * 2);
            sx += p2.x; sy += p2.y;
          }
          smem[SM_V + tid * 2] = sx * invs;
          smem[SM_V + tid * 2 + 1] = sy * invs;
        }
      }
      __syncthreads();
      if (wid < 8) {
        const int j = bid * 8 + wid;
        float acc = 0.f;
#pragma unroll
        for (int it = 0; it < 4; ++it) {
          acc += dot4(*(const float4*)(comb_w + (size_t)j * 2048 + it * 256 + lane * 4),
                      *(const float4*)(smem + SM_X + it * 256 + lane * 4));
          acc += dot4(*(const float4*)(comb_w + (size_t)j * 2048 + 1024 + it * 256 + lane * 4),
                      *(const float4*)(smem + SM_V + it * 256 + lane * 4));
        }
        acc = wred(acc);
        if (lane == 0) stcf(ws + INP_OFF + j, fmaxf(acc + comb_b[j], 0.f));
      }
      bar_arrive(bar, ++ep);
    }

    // ---- C: LSTM layer 0 (2 gate-rows/wave; h_prev = SM_H0) ----
    bar_wait_stage(bar, ep, smem + SM_V, ws + INP_OFF, 512, nullptr, nullptr, 0);
    {
      const int kk = wid >> 1, k = bid * 8 + kk;
#pragma unroll
      for (int gg2 = 0; gg2 < 2; ++gg2) {
        const int g = (wid & 1) * 2 + gg2;
        const float* wi = w_ih + (size_t)(g * HD + k) * HD;
        const float* wh = w_hh + (size_t)(g * HD + k) * HD;
        float acc = 0.f;
#pragma unroll
        for (int it = 0; it < 4; ++it) {
          acc += dot4(*(const float4*)(wi + it * 256 + lane * 4),
                      *(const float4*)(smem + SM_V + it * 256 + lane * 4));
          acc += dot4(*(const float4*)(wh + it * 256 + lane * 4),
                      *(const float4*)(smem + SM_H0 + it * 256 + lane * 4));
        }
        acc = wred(acc);
        if (lane == 0) smem[SM_G + kk * 4 + g] = acc;
      }
    }
    __syncthreads();
    if (tid < 8) {
      const int k = bid * 8 + tid;
      float gi = smem[SM_G + tid * 4 + 0] + b_ih[k]          + b_hh[k];
      float gf = smem[SM_G + tid * 4 + 1] + b_ih[HD + k]     + b_hh[HD + k];
      float gg = smem[SM_G + tid * 4 + 2] + b_ih[2 * HD + k] + b_hh[2 * HD + k];
      float go = smem[SM_G + tid * 4 + 3] + b_ih[3 * HD + k] + b_hh[3 * HD + k];
      float c = sigm(gf) * smem[SM_C0 + tid] + sigm(gi) * tanhf(gg);
      smem[SM_C0 + tid] = c;
      stcf(ws + H0_OFF + k, sigm(go) * tanhf(c));
    }
    bar_arrive(bar, ++ep);

    // ---- D: LSTM layer 1 (h_prev = SM_X == h1(t-1)) ----
    bar_wait_stage(bar, ep, smem + SM_V, ws + H0_OFF, 512, nullptr, nullptr, 0);
    if (t == 0) {   // h1(-1) = hidden[1], not x(0)=0
      if (tid < 512) *(float2*)(smem + SM_X + tid * 2) = *(const float2*)(hidden + HD + tid * 2);
      __syncthreads();
    }
    {
      const int kk = wid >> 1, k = bid * 8 + kk;
      const float* wi1 = w_ih + (size_t)4 * HD * HD;
      const float* wh1 = w_hh + (size_t)4 * HD * HD;
#pragma unroll
      for (int gg2 = 0; gg2 < 2; ++gg2) {
        const int g = (wid & 1) * 2 + gg2;
        const float* wi = wi1 + (size_t)(g * HD + k) * HD;
        const float* wh = wh1 + (size_t)(g * HD + k) * HD;
        float acc = 0.f;
#pragma unroll
        for (int it = 0; it < 4; ++it) {
          acc += dot4(*(const float4*)(wi + it * 256 + lane * 4),
                      *(const float4*)(smem + SM_V + it * 256 + lane * 4));
          acc += dot4(*(const float4*)(wh + it * 256 + lane * 4),
                      *(const float4*)(smem + SM_X + it * 256 + lane * 4));
        }
        acc = wred(acc);
        if (lane == 0) smem[SM_G + kk * 4 + g] = acc;
      }
    }
    __syncthreads();
    if (tid < 8) {
      const int k = bid * 8 + tid;
      float gi = smem[SM_G + tid * 4 + 0] + b_ih[4 * HD + k] + b_hh[4 * HD + k];
      float gf = smem[SM_G + tid * 4 + 1] + b_ih[5 * HD + k] + b_hh[5 * HD + k];
      float gg = smem[SM_G + tid * 4 + 2] + b_ih[6 * HD + k] + b_hh[6 * HD + k];
      float go = smem[SM_G + tid * 4 + 3] + b_ih[7 * HD + k] + b_hh[7 * HD + k];
      float c = sigm(gf) * smem[SM_C1 + tid] + sigm(gi) * tanhf(gg);
      smem[SM_C1 + tid] = c;
      stcf(xrow_st + k, sigm(go) * tanhf(c));
    }
    bar_arrive(bar, ++ep);
  }

  // ================= epilogue =================
  bar_wait_stage(bar, ep, nullptr, nullptr, 0, nullptr, nullptr, 0);
  if (tid < 8) {
    out[4096 + 2 * HD + bid * 8 + tid] = smem[SM_C0 + tid];
    out[4096 + 3 * HD + bid * 8 + tid] = smem[SM_C1 + tid];
  }
  if (bid == 0) {
    const float* xlast = (MODE == 2) ? (ws + XH_OFF + (size_t)SD * HD) : (ws + X_OFF);
    out[4096 + tid]      = ldcf(ws + H0_OFF + tid);
    out[4096 + HD + tid] = ldcf(xlast + tid);
  }
  if (MODE == 2) {
    // classifier for all steps: wave w -> step t = bid*16 + w
    const int t = bid * 16 + wid;
    const float* xr = ws + XH_OFF + (size_t)(t + 1) * HD;   // outs[t] = h1'(t)
    float2 xv[8];
#pragma unroll
    for (int p = 0; p < 8; ++p) xv[p] = *(const float2*)(xr + p * 128 + lane * 2);
#pragma unroll 1
    for (int o = 0; o < 64; ++o) {
      const float* wr = lin1_w + (size_t)o * HD;
      float acc = 0.f;
#pragma unroll
      for (int p = 0; p < 8; ++p) {
        float2 w2 = *(const float2*)(wr + p * 128 + lane * 2);
        acc += w2.x * xv[p].x + w2.y * xv[p].y;
      }
      acc = wred(acc);
      if (lane == 0) smem[SM_E + wid * 64 + o] = fmaxf(acc + lin1_b[o], 0.f);
    }
    float hv = smem[SM_E + wid * 64 + lane];
    float r0 = wred(hv * lin2_w[lane]);
    float r1 = wred(hv * lin2_w[64 + lane]);
    if (lane == 0) {
      float l0 = r0 + lin2_b[0], l1 = r1 + lin2_b[1];
      float m = fmaxf(l0, l1);
      float e0 = __expf(l0 - m), e1 = __expf(l1 - m);
      float inv = 1.f / (e0 + e1);
      out[(size_t)t * 2]     = e0 * inv;
      out[(size_t)t * 2 + 1] = e1 * inv;
    }
  } else if (bid == NBLK - 1) {
    const float* xlast = ws + X_OFF;
    if (tid < 512) *(float2*)(smem + SM_X + tid * 2) = ldc2(xlast + tid * 2);
    __syncthreads();
    classifier_block(smem + SM_X, lin1_w, lin1_b, lin2_w, lin2_b,
                     out + (size_t)(SD - 1) * 2, smem + SM_CLS);
  }
}

extern "C" void kernel_launch(void* const* d_in, const int* in_sizes, int n_in,
                              void* d_out, int out_size, void* d_ws, size_t ws_size,
                              hipStream_t stream) {
  const float* enc    = (const float*)d_in[0];
  const float* hidden = (const float*)d_in[1];
  const float* cell   = (const float*)d_in[2];
  const float* attn_w = (const float*)d_in[3];
  const float* attn_b = (const float*)d_in[4];
  const float* comb_w = (const float*)d_in[5];
  const float* comb_b = (const float*)d_in[6];
  const float* w_ih   = (const float*)d_in[7];
  const float* w_hh   = (const float*)d_in[8];
  const float* b_ih   = (const float*)d_in[9];
  const float* b_hh   = (const float*)d_in[10];
  const float* lin1_w = (const float*)d_in[11];
  const float* lin1_b = (const float*)d_in[12];
  const float* lin2_w = (const float*)d_in[13];
  const float* lin2_b = (const float*)d_in[14];
  float* out = (float*)d_out;
  float* ws  = (float*)d_ws;

  hipMemsetAsync(d_ws, 0, 4096, stream);
  if (ws_size >= WS_NEED_XH) {
    decoder_kernel<2><<<dim3(NBLK), dim3(TPB), 0, stream>>>(
        enc, attn_w, attn_b, comb_w, comb_b, w_ih, w_hh, b_ih, b_hh,
        lin1_w, lin1_b, lin2_w, lin2_b, hidden, cell, out, ws);
  } else if (ws_size >= WS_NEED_M) {
    decoder_kernel<1><<<dim3(NBLK), dim3(TPB), 0, stream>>>(
        enc, attn_w, attn_b, comb_w, comb_b, w_ih, w_hh, b_ih, b_hh,
        lin1_w, lin1_b, lin2_w, lin2_b, hidden, cell, out, ws);
  } else {
    decoder_kernel<0><<<dim3(NBLK), dim3(TPB), 0, stream>>>(
        enc, attn_w, attn_b, comb_w, comb_b, w_ih, w_hh, b_ih, b_hh,
        lin1_w, lin1_b, lin2_w, lin2_b, hidden, cell, out, ws);
  }
  (void)in_sizes; (void)n_in; (void)out_size;
}

// Round 5
// 23155.707 us; speedup vs baseline: 5.0179x; 5.0179x over previous
//
#include <hip/hip_runtime.h>
#include <math.h>

#define SD   2048
#define HD   1024
#define TPB  512    // 8 waves; launch_bounds(512,2) -> 256 VGPR budget for pinning
#define NBLK 256    // one block per CU

// ---- ws layout (float offsets); first 4KB = barrier flags/replicas ----
#define E_OFF   1024
#define H0_OFF  3072
#define INP_OFF 4096
#define X_OFF   5120
#define M_OFF   8192                     // M[1024][2048] = comb_w[:,1024:] @ enc^T
#define M_SZ    (HD * SD)
#define XH_OFF  (M_OFF + M_SZ)           // xh[(SD+1)][HD] history (MODE2)
#define XH_SZ   ((SD + 1) * HD)
#define WS_NEED_M  ((size_t)(M_OFF + M_SZ + HD) * 4)
#define WS_NEED_XH ((size_t)(XH_OFF + XH_SZ) * 4)

typedef unsigned long long u64;

// coherent accessors (bypass L1/L2, no cache-nuking fences)
__device__ __forceinline__ float ldcf(const float* p) {
  return __hip_atomic_load(p, __ATOMIC_RELAXED, __HIP_MEMORY_SCOPE_AGENT);
}
__device__ __forceinline__ float2 ldc2(const float* p) {
  u64 u = __hip_atomic_load((const u64*)p, __ATOMIC_RELAXED, __HIP_MEMORY_SCOPE_AGENT);
  union { u64 u; float2 f; } c; c.u = u; return c.f;
}
__device__ __forceinline__ void stcf(float* p, float v) {
  __hip_atomic_store(p, v, __ATOMIC_RELAXED, __HIP_MEMORY_SCOPE_AGENT);
}
__device__ __forceinline__ unsigned ldb(const unsigned* p) {
  return __hip_atomic_load(p, __ATOMIC_RELAXED, __HIP_MEMORY_SCOPE_AGENT);
}
__device__ __forceinline__ void stb(unsigned* p, unsigned v) {
  __hip_atomic_store(p, v, __ATOMIC_RELAXED, __HIP_MEMORY_SCOPE_AGENT);
}

__device__ __forceinline__ float dot4(float4 a, float4 b) {
  return a.x * b.x + a.y * b.y + a.z * b.z + a.w * b.w;
}
__device__ __forceinline__ float wred(float v) {
  v += __shfl_xor(v, 32, 64); v += __shfl_xor(v, 16, 64);
  v += __shfl_xor(v, 8, 64);  v += __shfl_xor(v, 4, 64);
  v += __shfl_xor(v, 2, 64);  v += __shfl_xor(v, 1, 64);
  return v;
}
__device__ __forceinline__ float sigm(float x) { return 1.0f / (1.0f + __expf(-x)); }

// ---- 2-hop barrier (round-3 proven): flags[0..255], replicas at 256+g*16.
// Master (block 0, wave 0) polls all flags flat-out; others poll one replica
// line with s_sleep backoff -> minimal fabric traffic.
__device__ __forceinline__ void bar_arrive(unsigned* bar, unsigned ep) {
  __syncthreads();                        // drains vmcnt -> sc1 stores visible
  if (threadIdx.x == 0) stb(bar + blockIdx.x, ep);
}
__device__ __forceinline__ void bar_wait(unsigned* bar, unsigned ep) {
  if (blockIdx.x == 0) {
    if (threadIdx.x < 64) {
      const int lane = threadIdx.x;
      unsigned m;
      do {
        unsigned a = ldb(bar + lane),       b = ldb(bar + 64 + lane);
        unsigned c = ldb(bar + 128 + lane), d = ldb(bar + 192 + lane);
        unsigned ab = a < b ? a : b, cd = c < d ? c : d;
        m = ab < cd ? ab : cd;
#pragma unroll
        for (int s = 32; s; s >>= 1) {
          unsigned o = (unsigned)__shfl_xor((int)m, s, 64);
          m = m < o ? m : o;
        }
      } while (m < ep);
      if (lane < 8) stb(bar + 256 + lane * 16, ep);
    }
  } else if (threadIdx.x == 0) {
    while (ldb(bar + 256 + (blockIdx.x & 7) * 16) < ep)
      __builtin_amdgcn_s_sleep(1);
  }
  __syncthreads();
}

// 8-wave classifier (MODE1 in-loop / final): probs = softmax(lin2@relu(lin1@x+b1)+b2)
__device__ void classifier8(const float* smx, const float* __restrict__ lin1_w,
                            const float* __restrict__ lin1_b,
                            const float* __restrict__ lin2_w,
                            const float* __restrict__ lin2_b,
                            float* __restrict__ out2, float* scratch) {
  const int tid = threadIdx.x, wid = tid >> 6, lane = tid & 63;
#pragma unroll
  for (int oi = 0; oi < 8; ++oi) {
    const int o = wid * 8 + oi;
    float acc = 0.f;
#pragma unroll
    for (int p = 0; p < 4; ++p)
      acc += dot4(*(const float4*)(lin1_w + (size_t)o * HD + p * 256 + lane * 4),
                  *(const float4*)(smx + p * 256 + lane * 4));
    acc = wred(acc);
    if (lane == 0) scratch[o] = fmaxf(acc + lin1_b[o], 0.f);
  }
  __syncthreads();
  if (tid < 64) {
    float hv = scratch[tid];
    float r0 = wred(hv * lin2_w[tid]);
    float r1 = wred(hv * lin2_w[64 + tid]);
    if (tid == 0) {
      float l0 = r0 + lin2_b[0], l1 = r1 + lin2_b[1];
      float m = fmaxf(l0, l1);
      float e0 = __expf(l0 - m), e1 = __expf(l1 - m);
      float inv = 1.f / (e0 + e1);
      out2[0] = e0 * inv; out2[1] = e1 * inv;
    }
  }
  __syncthreads();
}

template <int MODE>   // 2: xh history + epilogue classifier; 1: in-loop classifier
__global__ void __launch_bounds__(TPB, 2)
decoder_kernel(const float* __restrict__ enc, const float* __restrict__ attn_w,
               const float* __restrict__ attn_b, const float* __restrict__ comb_w,
               const float* __restrict__ comb_b, const float* __restrict__ w_ih,
               const float* __restrict__ w_hh, const float* __restrict__ b_ih,
               const float* __restrict__ b_hh, const float* __restrict__ lin1_w,
               const float* __restrict__ lin1_b, const float* __restrict__ lin2_w,
               const float* __restrict__ lin2_b, const float* __restrict__ hidden,
               const float* __restrict__ cell, float* __restrict__ out,
               float* __restrict__ ws) {
  __shared__ __align__(16) float lds_x[HD];
  __shared__ __align__(16) float lds_h0[HD];
  __shared__ __align__(16) float lds_e[SD];
  __shared__ __align__(16) float lds_v[HD];
  __shared__ __align__(16) float lds_big[8 * HD];   // prologue enc / classifier hid
  __shared__ float sg[16], sb[24], bs0[16], bs1[16], scb[4], sc0[4], sc1_[4];

  const int tid = threadIdx.x, wid = tid >> 6, lane = tid & 63;
  const int bid = blockIdx.x;
  unsigned* bar = (unsigned*)ws;
  unsigned ep = 0;

  // ================= prologue: M = comb_w[:,1024:] @ enc^T =================
  {
    const int j0 = (bid >> 3) * 32, i0 = (bid & 7) * 256;
    // pin this wave's 4 comb rows (64 VGPR, prologue-only lifetime)
    float4 cw0[4], cw1[4], cw2[4], cw3[4];
#pragma unroll
    for (int p = 0; p < 4; ++p) {
      cw0[p] = *(const float4*)(comb_w + (size_t)(j0 + wid * 4 + 0) * 2048 + 1024 + p * 256 + lane * 4);
      cw1[p] = *(const float4*)(comb_w + (size_t)(j0 + wid * 4 + 1) * 2048 + 1024 + p * 256 + lane * 4);
      cw2[p] = *(const float4*)(comb_w + (size_t)(j0 + wid * 4 + 2) * 2048 + 1024 + p * 256 + lane * 4);
      cw3[p] = *(const float4*)(comb_w + (size_t)(j0 + wid * 4 + 3) * 2048 + 1024 + p * 256 + lane * 4);
    }
    for (int ib = 0; ib < 32; ++ib) {
      const int rl = tid >> 6, cs = (tid & 63) * 16;
      const float* src = enc + (size_t)(i0 + ib * 8 + rl) * HD + cs;
#pragma unroll
      for (int q = 0; q < 4; ++q)
        *(float4*)(lds_big + rl * HD + cs + q * 4) = *(const float4*)(src + q * 4);
      __syncthreads();
#pragma unroll 1
      for (int ii = 0; ii < 8; ++ii) {
        float a0 = 0.f, a1 = 0.f, a2 = 0.f, a3 = 0.f;
#pragma unroll
        for (int p = 0; p < 4; ++p) {
          float4 e4 = *(const float4*)(lds_big + ii * HD + p * 256 + lane * 4);
          a0 += dot4(cw0[p], e4); a1 += dot4(cw1[p], e4);
          a2 += dot4(cw2[p], e4); a3 += dot4(cw3[p], e4);
        }
        a0 = wred(a0); a1 = wred(a1); a2 = wred(a2); a3 = wred(a3);
        if (lane == 0) {
          const int i = i0 + ib * 8 + ii;
          stcf(ws + M_OFF + (size_t)(j0 + wid * 4 + 0) * SD + i, a0);
          stcf(ws + M_OFF + (size_t)(j0 + wid * 4 + 1) * SD + i, a1);
          stcf(ws + M_OFF + (size_t)(j0 + wid * 4 + 2) * SD + i, a2);
          stcf(ws + M_OFF + (size_t)(j0 + wid * 4 + 3) * SD + i, a3);
        }
      }
      __syncthreads();
    }
  }
  // recurrent-state init
  float* xrow0 = (MODE == 2) ? (ws + XH_OFF) : (ws + X_OFF);
  if (bid == 0) { stcf(xrow0 + tid, 0.f); stcf(xrow0 + 512 + tid, 0.f); }
  *(float2*)(lds_h0 + tid * 2) = *(const float2*)(hidden + tid * 2);
  if (tid < 16) {
    const int kl = tid >> 2, g = tid & 3, k = bid * 4 + kl;
    bs0[tid] = b_ih[g * HD + k] + b_hh[g * HD + k];
    bs1[tid] = b_ih[4 * HD + g * HD + k] + b_hh[4 * HD + g * HD + k];
  }
  if (tid < 4) {
    scb[tid]  = comb_b[bid * 4 + tid];
    sc0[tid]  = cell[bid * 4 + tid];
    sc1_[tid] = cell[HD + bid * 4 + tid];
  }
  ++ep; bar_arrive(bar, ep); bar_wait(bar, ep);

  // ================= pin per-wave weight rows in registers =================
  const int gw = bid * 8 + wid;                 // attn row
  float4 wa[8]; float ab = attn_b[gw];
#pragma unroll
  for (int p = 0; p < 8; ++p)
    wa[p] = *(const float4*)(attn_w + (size_t)gw * 2048 + p * 256 + lane * 4);
  const int jB = bid * 4 + (wid >> 1), half = wid & 1;   // comb/M row (2 waves/row)
  float4 wxp[2], wmp[4];
#pragma unroll
  for (int p = 0; p < 2; ++p)
    wxp[p] = *(const float4*)(comb_w + (size_t)jB * 2048 + half * 512 + p * 256 + lane * 4);
#pragma unroll
  for (int p = 0; p < 4; ++p)
    wmp[p] = *(const float4*)(ws + M_OFF + (size_t)jB * SD + half * 1024 + p * 256 + lane * 4);
  const int kC = bid * 4 + (wid >> 1), gb = (wid & 1) * 2; // LSTM row k, gates gb,gb+1
  float4 wi0A[4], wi0B[4], wh0A[4], wh0B[4], wi1A[4], wi1B[4], wh1A[4], wh1B[4];
#pragma unroll
  for (int p = 0; p < 4; ++p) {
    wi0A[p] = *(const float4*)(w_ih + (size_t)((gb + 0) * HD + kC) * HD + p * 256 + lane * 4);
    wi0B[p] = *(const float4*)(w_ih + (size_t)((gb + 1) * HD + kC) * HD + p * 256 + lane * 4);
    wh0A[p] = *(const float4*)(w_hh + (size_t)((gb + 0) * HD + kC) * HD + p * 256 + lane * 4);
    wh0B[p] = *(const float4*)(w_hh + (size_t)((gb + 1) * HD + kC) * HD + p * 256 + lane * 4);
    wi1A[p] = *(const float4*)(w_ih + (size_t)4 * HD * HD + (size_t)((gb + 0) * HD + kC) * HD + p * 256 + lane * 4);
    wi1B[p] = *(const float4*)(w_ih + (size_t)4 * HD * HD + (size_t)((gb + 1) * HD + kC) * HD + p * 256 + lane * 4);
    wh1A[p] = *(const float4*)(w_hh + (size_t)4 * HD * HD + (size_t)((gb + 0) * HD + kC) * HD + p * 256 + lane * 4);
    wh1B[p] = *(const float4*)(w_hh + (size_t)4 * HD * HD + (size_t)((gb + 1) * HD + kC) * HD + p * 256 + lane * 4);
  }

  // ================= main loop: 4 barrier-phases/step =================
  for (int t = 0; t < SD; ++t) {
    const float* xrow_ld = (MODE == 2) ? (ws + XH_OFF + (size_t)t * HD) : (ws + X_OFF);
    float* xrow_st = (MODE == 2) ? (ws + XH_OFF + (size_t)(t + 1) * HD) : (ws + X_OFF);

    // ---- A: e[gw] = exp(attn_row . [x;h0] + b) ----
    *(float2*)(lds_x + tid * 2) = ldc2(xrow_ld + tid * 2);
    __syncthreads();
    {
      float acc = 0.f;
#pragma unroll
      for (int p = 0; p < 4; ++p)
        acc += dot4(wa[p], *(const float4*)(lds_x + p * 256 + lane * 4));
#pragma unroll
      for (int p = 0; p < 4; ++p)
        acc += dot4(wa[4 + p], *(const float4*)(lds_h0 + p * 256 + lane * 4));
      acc = wred(acc);
      if (lane == 0) stcf(ws + E_OFF + gw, __expf(acc + ab));
    }
    ++ep; bar_arrive(bar, ep);
    if (MODE == 1 && bid == NBLK - 1 && t > 0)
      classifier8(lds_x, lin1_w, lin1_b, lin2_w, lin2_b,
                  out + (size_t)(t - 1) * 2, lds_big);
    bar_wait(bar, ep);

    // ---- B: inp[j] = relu(Wx.x + (M.e)/sum(e) + b) ----
    *(float2*)(lds_e + tid * 2)        = ldc2(ws + E_OFF + tid * 2);
    *(float2*)(lds_e + 1024 + tid * 2) = ldc2(ws + E_OFF + 1024 + tid * 2);
    __syncthreads();
    {
      float axh = 0.f, amh = 0.f, esh = 0.f;
#pragma unroll
      for (int p = 0; p < 2; ++p)
        axh += dot4(wxp[p], *(const float4*)(lds_x + half * 512 + p * 256 + lane * 4));
#pragma unroll
      for (int p = 0; p < 4; ++p) {
        float4 e4 = *(const float4*)(lds_e + half * 1024 + p * 256 + lane * 4);
        amh += dot4(wmp[p], e4);
        esh += e4.x + e4.y + e4.z + e4.w;
      }
      axh = wred(axh); amh = wred(amh); esh = wred(esh);
      if (lane == 0) { sb[wid * 3] = axh; sb[wid * 3 + 1] = amh; sb[wid * 3 + 2] = esh; }
    }
    __syncthreads();
    if (tid < 4) {
      float ax = sb[tid * 6] + sb[tid * 6 + 3];
      float am = sb[tid * 6 + 1] + sb[tid * 6 + 4];
      float es = sb[tid * 6 + 2] + sb[tid * 6 + 5];
      stcf(ws + INP_OFF + bid * 4 + tid, fmaxf(ax + am / es + scb[tid], 0.f));
    }
    ++ep; bar_arrive(bar, ep); bar_wait(bar, ep);

    // ---- C: LSTM layer 0 (pinned rows; h_prev = lds_h0) ----
    *(float2*)(lds_v + tid * 2) = ldc2(ws + INP_OFF + tid * 2);
    __syncthreads();
    {
      float a0 = 0.f, a1 = 0.f;
#pragma unroll
      for (int p = 0; p < 4; ++p) {
        float4 v4 = *(const float4*)(lds_v + p * 256 + lane * 4);
        float4 h4 = *(const float4*)(lds_h0 + p * 256 + lane * 4);
        a0 += dot4(wi0A[p], v4) + dot4(wh0A[p], h4);
        a1 += dot4(wi0B[p], v4) + dot4(wh0B[p], h4);
      }
      a0 = wred(a0); a1 = wred(a1);
      if (lane == 0) { sg[(wid >> 1) * 4 + gb] = a0; sg[(wid >> 1) * 4 + gb + 1] = a1; }
    }
    __syncthreads();
    if (tid < 4) {
      float gi = sg[tid * 4 + 0] + bs0[tid * 4 + 0];
      float gf = sg[tid * 4 + 1] + bs0[tid * 4 + 1];
      float gg = sg[tid * 4 + 2] + bs0[tid * 4 + 2];
      float go = sg[tid * 4 + 3] + bs0[tid * 4 + 3];
      float c = sigm(gf) * sc0[tid] + sigm(gi) * tanhf(gg);
      sc0[tid] = c;
      stcf(ws + H0_OFF + bid * 4 + tid, sigm(go) * tanhf(c));
    }
    ++ep; bar_arrive(bar, ep); bar_wait(bar, ep);

    // ---- D: LSTM layer 1 (h_prev = lds_x == h1(t-1)) ----
    *(float2*)(lds_h0 + tid * 2) = ldc2(ws + H0_OFF + tid * 2);
    if (t == 0)   // h1(-1) = hidden[1], not x(0)=0
      *(float2*)(lds_x + tid * 2) = *(const float2*)(hidden + HD + tid * 2);
    __syncthreads();
    {
      float a0 = 0.f, a1 = 0.f;
#pragma unroll
      for (int p = 0; p < 4; ++p) {
        float4 v4 = *(const float4*)(lds_h0 + p * 256 + lane * 4);
        float4 h4 = *(const float4*)(lds_x + p * 256 + lane * 4);
        a0 += dot4(wi1A[p], v4) + dot4(wh1A[p], h4);
        a1 += dot4(wi1B[p], v4) + dot4(wh1B[p], h4);
      }
      a0 = wred(a0); a1 = wred(a1);
      if (lane == 0) { sg[(wid >> 1) * 4 + gb] = a0; sg[(wid >> 1) * 4 + gb + 1] = a1; }
    }
    __syncthreads();
    if (tid < 4) {
      float gi = sg[tid * 4 + 0] + bs1[tid * 4 + 0];
      float gf = sg[tid * 4 + 1] + bs1[tid * 4 + 1];
      float gg = sg[tid * 4 + 2] + bs1[tid * 4 + 2];
      float go = sg[tid * 4 + 3] + bs1[tid * 4 + 3];
      float c = sigm(gf) * sc1_[tid] + sigm(gi) * tanhf(gg);
      sc1_[tid] = c;
      stcf(xrow_st + bid * 4 + tid, sigm(go) * tanhf(c));
    }
    ++ep; bar_arrive(bar, ep); bar_wait(bar, ep);
  }

  // ================= epilogue =================
  if (tid < 4) {
    out[4096 + 2 * HD + bid * 4 + tid] = sc0[tid];
    out[4096 + 3 * HD + bid * 4 + tid] = sc1_[tid];
  }
  if (bid == 0) {
    *(float2*)(out + 4096 + tid * 2) = *(const float2*)(lds_h0 + tid * 2);  // h0 final
    const float* xf = (MODE == 2) ? (ws + XH_OFF + (size_t)SD * HD) : (ws + X_OFF);
    float2 x2 = ldc2(xf + tid * 2);
    *(float2*)(out + 4096 + HD + tid * 2) = x2;                             // h1 final
  }
  if (MODE == 2) {
    // classifier for all steps: wave -> step tt = bid*8 + wid; outs[tt] = xh[tt+1]
    const int tt = bid * 8 + wid;
    const float* xr = ws + XH_OFF + (size_t)(tt + 1) * HD;
    float4 xv[4];
#pragma unroll
    for (int p = 0; p < 4; ++p) xv[p] = *(const float4*)(xr + p * 256 + lane * 4);
    float* hid = lds_big + wid * 64;
#pragma unroll 2
    for (int o = 0; o < 64; ++o) {
      const float* wo = lin1_w + (size_t)o * HD;
      float acc = 0.f;
#pragma unroll
      for (int p = 0; p < 4; ++p)
        acc += dot4(*(const float4*)(wo + p * 256 + lane * 4), xv[p]);
      acc = wred(acc);
      if (lane == 0) hid[o] = fmaxf(acc + lin1_b[o], 0.f);
    }
    float hv = hid[lane];
    float r0 = wred(hv * lin2_w[lane]);
    float r1 = wred(hv * lin2_w[64 + lane]);
    if (lane == 0) {
      float l0 = r0 + lin2_b[0], l1 = r1 + lin2_b[1];
      float m = fmaxf(l0, l1);
      float e0 = __expf(l0 - m), e1 = __expf(l1 - m);
      float inv = 1.f / (e0 + e1);
      out[(size_t)tt * 2]     = e0 * inv;
      out[(size_t)tt * 2 + 1] = e1 * inv;
    }
  } else if (bid == NBLK - 1) {
    *(float2*)(lds_x + tid * 2) = ldc2(ws + X_OFF + tid * 2);
    __syncthreads();
    classifier8(lds_x, lin1_w, lin1_b, lin2_w, lin2_b,
                out + (size_t)(SD - 1) * 2, lds_big);
  }
}

extern "C" void kernel_launch(void* const* d_in, const int* in_sizes, int n_in,
                              void* d_out, int out_size, void* d_ws, size_t ws_size,
                              hipStream_t stream) {
  const float* enc    = (const float*)d_in[0];
  const float* hidden = (const float*)d_in[1];
  const float* cell   = (const float*)d_in[2];
  const float* attn_w = (const float*)d_in[3];
  const float* attn_b = (const float*)d_in[4];
  const float* comb_w = (const float*)d_in[5];
  const float* comb_b = (const float*)d_in[6];
  const float* w_ih   = (const float*)d_in[7];
  const float* w_hh   = (const float*)d_in[8];
  const float* b_ih   = (const float*)d_in[9];
  const float* b_hh   = (const float*)d_in[10];
  const float* lin1_w = (const float*)d_in[11];
  const float* lin1_b = (const float*)d_in[12];
  const float* lin2_w = (const float*)d_in[13];
  const float* lin2_b = (const float*)d_in[14];
  float* out = (float*)d_out;
  float* ws  = (float*)d_ws;

  hipMemsetAsync(d_ws, 0, 4096, stream);   // barrier flags + replicas
  if (ws_size >= WS_NEED_XH) {
    decoder_kernel<2><<<dim3(NBLK), dim3(TPB), 0, stream>>>(
        enc, attn_w, attn_b, comb_w, comb_b, w_ih, w_hh, b_ih, b_hh,
        lin1_w, lin1_b, lin2_w, lin2_b, hidden, cell, out, ws);
  } else {
    decoder_kernel<1><<<dim3(NBLK), dim3(TPB), 0, stream>>>(
        enc, attn_w, attn_b, comb_w, comb_b, w_ih, w_hh, b_ih, b_hh,
        lin1_w, lin1_b, lin2_w, lin2_b, hidden, cell, out, ws);
  }
  (void)in_sizes; (void)n_in; (void)out_size;
}